// Round 3
// baseline (271.833 us; speedup 1.0000x reference)
//
#include <hip/hip_runtime.h>
#include <hip/hip_bf16.h>

typedef __attribute__((ext_vector_type(8))) short bh8;
typedef __attribute__((ext_vector_type(4))) float f32x4;

#define GBL(p) (const __attribute__((address_space(1))) void*)(p)
#define LDSP(p) (__attribute__((address_space(3))) void*)(p)

__device__ __forceinline__ ushort f2bf(float f){
  union { float f; unsigned u; } v; v.f = f;
  unsigned u = v.u;
  return (ushort)((u + 0x7fffu + ((u >> 16) & 1u)) >> 16);
}

// ---------------- prologue: cast x to bf16 ----------------
__global__ __launch_bounds__(256) void cast_x_kernel(const float4* __restrict__ in,
                                                     ushort* __restrict__ out){
  int i = blockIdx.x * 256 + threadIdx.x;
  float4 v = in[i];
  ushort4 o;
  o.x = f2bf(v.x); o.y = f2bf(v.y); o.z = f2bf(v.z); o.w = f2bf(v.w);
  *(ushort4*)&out[(size_t)i * 4] = o;
}

// ---------------- prologue: transpose-cast W [R][C] fp32 -> [C][R] bf16 ----------------
__global__ __launch_bounds__(256) void transpose_cast_kernel(const float* __restrict__ in,
                                                             ushort* __restrict__ out,
                                                             int R, int C){
  __shared__ float tile[32][33];
  int bx = blockIdx.x * 32;
  int by = blockIdx.y * 32;
  int tx = threadIdx.x, ty = threadIdx.y;  // 32x8
  #pragma unroll
  for (int i = 0; i < 32; i += 8)
    tile[ty + i][tx] = in[(size_t)(by + ty + i) * C + bx + tx];
  __syncthreads();
  #pragma unroll
  for (int i = 0; i < 32; i += 8)
    out[(size_t)(bx + ty + i) * R + by + tx] = f2bf(tile[tx][ty + i]);
}

// ---------------- GEMM1: qkv = x @ Wqkv + b ----------------
// PROVEN structure: 128x128 tile, 256 thr, 4 blocks/CU (TLP hides staging).
// XOR-swizzled LDS: tile [128 rows][8 units of 16B], phys unit = row*8 + (cu^(row&7)).
__global__ __launch_bounds__(256) void gemm_qkv_kernel(
    const ushort* __restrict__ A,   // [8192][1024] bf16
    const ushort* __restrict__ Bt,  // [3072][1024] bf16 (W^T)
    const float* __restrict__ bias, // [3072]
    ushort* __restrict__ Qd, ushort* __restrict__ Kd, ushort* __restrict__ Vt)
{
  constexpr int K = 1024;
  __shared__ ushort sA[8192];   // [128][8 units] swizzled
  __shared__ ushort sB[8192];
  const int tid = threadIdx.x;
  const int lane = tid & 63, wave = tid >> 6;
  const int quad = lane >> 4, l16 = lane & 15;
  const int rx7 = l16 & 7;
  const int wm = (wave >> 1) * 64, wn = (wave & 1) * 64;
  const size_t aBase = (size_t)blockIdx.x * 128 * K;
  const size_t bBase = (size_t)blockIdx.y * 128 * K;
  f32x4 acc[4][4] = {};
  for (int k0 = 0; k0 < K; k0 += 64){
    #pragma unroll
    for (int c = 0; c < 4; c++){
      int u = c * 256 + tid;
      int row = u >> 3, cu = (u & 7) ^ (row & 7);
      __builtin_amdgcn_global_load_lds(GBL(A + aBase + (size_t)row * K + k0 + cu * 8),
                                       LDSP(&sA[u * 8]), 16, 0, 0);
      __builtin_amdgcn_global_load_lds(GBL(Bt + bBase + (size_t)row * K + k0 + cu * 8),
                                       LDSP(&sB[u * 8]), 16, 0, 0);
    }
    __syncthreads();
    #pragma unroll
    for (int ks = 0; ks < 2; ks++){
      bh8 af[4], bf[4];
      #pragma unroll
      for (int i = 0; i < 4; i++){
        int row = wm + i * 16 + l16;
        af[i] = *(const bh8*)&sA[row * 64 + (((ks * 4 + quad) ^ rx7) << 3)];
      }
      #pragma unroll
      for (int j = 0; j < 4; j++){
        int row = wn + j * 16 + l16;
        bf[j] = *(const bh8*)&sB[row * 64 + (((ks * 4 + quad) ^ rx7) << 3)];
      }
      #pragma unroll
      for (int i = 0; i < 4; i++)
        #pragma unroll
        for (int j = 0; j < 4; j++)
          acc[i][j] = __builtin_amdgcn_mfma_f32_16x16x32_bf16(af[i], bf[j], acc[i][j], 0, 0, 0);
    }
    __syncthreads();
  }
  const int whichBlk = (blockIdx.y * 128) >> 10;  // 0=Q 1=K 2=V (uniform per block)
  #pragma unroll
  for (int i = 0; i < 4; i++){
    int mg = blockIdx.x * 128 + wm + i * 16 + quad * 4;
    int bb = mg >> 11, t0 = mg & 2047;
    #pragma unroll
    for (int j = 0; j < 4; j++){
      int ng = blockIdx.y * 128 + wn + j * 16 + l16;
      float bv = bias[ng];
      int h = (ng >> 6) & 15;
      int dh = ng & 63;
      if (whichBlk == 2){
        ushort4 o;
        o.x = f2bf(acc[i][j][0] + bv);
        o.y = f2bf(acc[i][j][1] + bv);
        o.z = f2bf(acc[i][j][2] + bv);
        o.w = f2bf(acc[i][j][3] + bv);
        *(ushort4*)&Vt[((size_t)((bb * 16 + h) * 64 + dh)) * 2048 + t0] = o;
      } else {
        ushort* dst = (whichBlk == 0) ? Qd : Kd;
        // Q: fold 1/sqrt(64) * log2(e) so flash can use bare exp2
        float sc = (whichBlk == 0) ? 0.18033688f : 1.0f;
        #pragma unroll
        for (int r = 0; r < 4; r++)
          dst[((size_t)((bb * 16 + h) * 2048 + t0 + r) << 6) + dh] = f2bf((acc[i][j][r] + bv) * sc);
      }
    }
  }
}

// ---------------- flash attention v7 (causal, T12 in-register P) ----------------
// Swapped QK^T: S^T = mfma(A=K, B=Q) puts a full P-column (fixed q = l16) in-lane:
//  - mask / exp2 / row-sum are lane-local (1 lsum scalar, 2-shuffle reduce, 1 rcp)
//  - P -> PV B-operand built in-register (cvt_pk + xor32/xor16 shuffles + cndmask);
//    the sP LDS buffer and its write->read serialization are gone
//  - PV computes O^T: r=0..3 land at consecutive dh -> ushort4 output stores
// Routing algebra: PV frag ks word m = w[2ks+b5][m&1] taken from source lane
// (b4' = m>>1, b5' = b4); built as R0/R1 = xor32-merge, then xor16 + per-lane select.
__global__ __launch_bounds__(256, 4) void flash_attn_kernel(
    const ushort* __restrict__ Qd, const ushort* __restrict__ Kd,
    const ushort* __restrict__ Vt, ushort* __restrict__ Od)
{
  __shared__ ushort sK[2][4096];
  __shared__ ushort sV[2][4096];
  const int tid = threadIdx.x;
  const int lane = tid & 63, wave = tid >> 6;
  const int quad = lane >> 4, l16 = lane & 15;
  const int b4 = quad & 1, b5 = quad >> 1;
  const int bh = blockIdx.x, pairI = blockIdx.y;
  const size_t base = (size_t)bh * (2048 * 64);
  const float SINIT = -7.2134752f;   // -5 * log2(e)

  const int p0 = tid, p1 = 256 + tid;
  const int r0 = p0 >> 3, c0 = (p0 & 7) ^ (r0 & 7);
  const int r1 = p1 >> 3, c1 = (p1 & 7) ^ (r1 & 7);
  const ushort* kp0 = Kd + base + r0 * 64 + c0 * 8;
  const ushort* kp1 = Kd + base + r1 * 64 + c1 * 8;
  const ushort* vp0 = Vt + base + (size_t)r0 * 2048 + c0 * 8;
  const ushort* vp1 = Vt + base + (size_t)r1 * 2048 + c1 * 8;

  const int b = bh >> 4, h = bh & 15;

  // loop-invariant LDS fragment offsets (ushort index); same formula for K and V
  int foff[2][4];
  #pragma unroll
  for (int ks = 0; ks < 2; ks++)
    #pragma unroll
    for (int j = 0; j < 4; j++){
      int row = j * 16 + l16;
      foff[ks][j] = (row * 8 + ((ks * 4 + quad) ^ (row & 7))) * 8;
    }

  #pragma unroll 1
  for (int phase = 0; phase < 2; phase++){
    const int qt = phase ? pairI : (31 - pairI);
    const ushort* qrow = Qd + base + (size_t)(qt * 64 + wave * 16 + l16) * 64 + quad * 8;
    bh8 qf0 = *(const bh8*)qrow;
    bh8 qf1 = *(const bh8*)(qrow + 32);

    f32x4 Oacc[4] = {};
    float lsum = 0.f;

    __syncthreads();
    __builtin_amdgcn_global_load_lds(GBL(kp0), LDSP(&sK[0][p0 * 8]), 16, 0, 0);
    __builtin_amdgcn_global_load_lds(GBL(kp1), LDSP(&sK[0][p1 * 8]), 16, 0, 0);
    __builtin_amdgcn_global_load_lds(GBL(vp0), LDSP(&sV[0][p0 * 8]), 16, 0, 0);
    __builtin_amdgcn_global_load_lds(GBL(vp1), LDSP(&sV[0][p1 * 8]), 16, 0, 0);

    #pragma unroll 1
    for (int kt = 0; kt <= qt; kt++){
      const int buf = kt & 1;
      __syncthreads();
      if (kt < qt){
        const int nb = buf ^ 1;
        __builtin_amdgcn_global_load_lds(GBL(kp0 + (kt + 1) * 4096), LDSP(&sK[nb][p0 * 8]), 16, 0, 0);
        __builtin_amdgcn_global_load_lds(GBL(kp1 + (kt + 1) * 4096), LDSP(&sK[nb][p1 * 8]), 16, 0, 0);
        __builtin_amdgcn_global_load_lds(GBL(vp0 + (kt + 1) * 64),   LDSP(&sV[nb][p0 * 8]), 16, 0, 0);
        __builtin_amdgcn_global_load_lds(GBL(vp1 + (kt + 1) * 64),   LDSP(&sV[nb][p1 * 8]), 16, 0, 0);
      }
      // ---- QK^T, swapped: S^T[t][q], lane holds t = j*16+quad*4+r at q = wave*16+l16
      f32x4 S[4];
      #pragma unroll
      for (int j = 0; j < 4; j++) S[j] = (f32x4){SINIT, SINIT, SINIT, SINIT};
      __builtin_amdgcn_s_setprio(1);
      #pragma unroll
      for (int ks = 0; ks < 2; ks++){
        bh8 aq = ks ? qf1 : qf0;
        #pragma unroll
        for (int j = 0; j < 4; j++){
          bh8 bk = *(const bh8*)&sK[buf][foff[ks][j]];
          S[j] = __builtin_amdgcn_mfma_f32_16x16x32_bf16(bk, aq, S[j], 0, 0, 0);
        }
      }
      __builtin_amdgcn_s_setprio(0);
      if (kt == qt){
        const int relq = wave * 16 + l16;
        #pragma unroll
        for (int j = 0; j < 4; j++)
          #pragma unroll
          for (int r = 0; r < 4; r++){
            int relt = j * 16 + quad * 4 + r;
            if (relt > relq) S[j][r] = -1e30f;
          }
      }
      // ---- exp2 + lane-local row-sum + pack to bf16 pairs
      unsigned w[4][2];
      #pragma unroll
      for (int j = 0; j < 4; j++){
        float pv[4];
        #pragma unroll
        for (int r = 0; r < 4; r++){
          pv[r] = exp2f(S[j][r]);     // bare v_exp_f32
          lsum += pv[r];
        }
        __hip_bfloat162 pk0 = __float22bfloat162_rn({pv[0], pv[1]});
        __hip_bfloat162 pk1 = __float22bfloat162_rn({pv[2], pv[3]});
        w[j][0] = *(unsigned*)&pk0;
        w[j][1] = *(unsigned*)&pk1;
      }
      // ---- PV: build P frag in-register per ks, then 4 MFMA (A = V-frag)
      #pragma unroll
      for (int ks = 0; ks < 2; ks++){
        unsigned pw[4];
        #pragma unroll
        for (int rp = 0; rp < 2; rp++){
          unsigned t0 = w[2 * ks][rp], t1 = w[2 * ks + 1][rp];
          unsigned a  = (unsigned)__shfl_xor((int)t0, 32, 64);
          unsigned bb2= (unsigned)__shfl_xor((int)t1, 32, 64);
          unsigned R0 = b5 ? bb2 : t0;   // w[2ks+b5][rp] from (b4'=b4, b5'=0)
          unsigned R1 = b5 ? t1  : a;    // w[2ks+b5][rp] from (b4'=b4, b5'=1)
          unsigned c  = (unsigned)__shfl_xor((int)R0, 16, 64);
          unsigned d  = (unsigned)__shfl_xor((int)R1, 16, 64);
          pw[rp]     = b4 ? d  : R0;     // word m=rp:   src (b4'=0, b5'=b4)
          pw[2 + rp] = b4 ? R1 : c;      // word m=2+rp: src (b4'=1, b5'=b4)
        }
        union { unsigned u[4]; bh8 v; } pu;
        pu.u[0] = pw[0]; pu.u[1] = pw[1]; pu.u[2] = pw[2]; pu.u[3] = pw[3];
        __builtin_amdgcn_s_setprio(1);
        #pragma unroll
        for (int j = 0; j < 4; j++){
          bh8 av = *(const bh8*)&sV[buf][foff[ks][j]];
          Oacc[j] = __builtin_amdgcn_mfma_f32_16x16x32_bf16(av, pu.v, Oacc[j], 0, 0, 0);
        }
        __builtin_amdgcn_s_setprio(0);
      }
    }
    // ---- denominator: lane-local partial + 2-shuffle quad reduce
    float s = lsum;
    s += __shfl_xor(s, 16, 64);
    s += __shfl_xor(s, 32, 64);
    float lr = 1.0f / s;
    // ---- O^T epilogue: r=0..3 at consecutive dh -> ushort4 stores
    const int qg = qt * 64 + wave * 16 + l16;
    #pragma unroll
    for (int j = 0; j < 4; j++){
      ushort4 o;
      o.x = f2bf(Oacc[j][0] * lr);
      o.y = f2bf(Oacc[j][1] * lr);
      o.z = f2bf(Oacc[j][2] * lr);
      o.w = f2bf(Oacc[j][3] * lr);
      *(ushort4*)&Od[(size_t)(b * 2048 + qg) * 1024 + h * 64 + j * 16 + quad * 4] = o;
    }
  }
}

// ---------------- GEMM2: out = O @ Wo + b_o (fp32 out) ----------------
// 128x128 tile (mirrors proven gemm_qkv structure).
// Grid (64,8) = 512 blocks = 2 exact rounds, 4 blocks/CU; XOR-swizzled LDS.
__global__ __launch_bounds__(256) void gemm_out_kernel(
    const ushort* __restrict__ A,   // [8192][1024] bf16 (O)
    const ushort* __restrict__ Bt,  // [1024][1024] bf16 (Wo^T)
    const float* __restrict__ bias, // [1024]
    float* __restrict__ out)        // [8192][1024] fp32
{
  constexpr int K = 1024;
  __shared__ ushort sA[8192];   // [128][8] swizzled
  __shared__ ushort sB[8192];   // [128][8] swizzled
  const int tid = threadIdx.x;
  const int lane = tid & 63, wave = tid >> 6;
  const int quad = lane >> 4, l16 = lane & 15;
  const int rx7 = l16 & 7;
  const int wm = (wave >> 1) * 64, wn = (wave & 1) * 64;
  const size_t aBase = (size_t)blockIdx.x * 128 * K;
  const size_t bBase = (size_t)blockIdx.y * 128 * K;
  f32x4 acc[4][4] = {};
  for (int k0 = 0; k0 < K; k0 += 64){
    #pragma unroll
    for (int c = 0; c < 4; c++){
      int u = c * 256 + tid;
      int row = u >> 3, cu = (u & 7) ^ (row & 7);
      __builtin_amdgcn_global_load_lds(GBL(A + aBase + (size_t)row * K + k0 + cu * 8),
                                       LDSP(&sA[u * 8]), 16, 0, 0);
      __builtin_amdgcn_global_load_lds(GBL(Bt + bBase + (size_t)row * K + k0 + cu * 8),
                                       LDSP(&sB[u * 8]), 16, 0, 0);
    }
    __syncthreads();
    #pragma unroll
    for (int ks = 0; ks < 2; ks++){
      bh8 af[4], bf[4];
      #pragma unroll
      for (int i = 0; i < 4; i++){
        int row = wm + i * 16 + l16;
        af[i] = *(const bh8*)&sA[row * 64 + (((ks * 4 + quad) ^ rx7) << 3)];
      }
      #pragma unroll
      for (int j = 0; j < 4; j++){
        int row = wn + j * 16 + l16;
        bf[j] = *(const bh8*)&sB[row * 64 + (((ks * 4 + quad) ^ rx7) << 3)];
      }
      #pragma unroll
      for (int i = 0; i < 4; i++)
        #pragma unroll
        for (int j = 0; j < 4; j++)
          acc[i][j] = __builtin_amdgcn_mfma_f32_16x16x32_bf16(af[i], bf[j], acc[i][j], 0, 0, 0);
    }
    __syncthreads();
  }
  #pragma unroll
  for (int i = 0; i < 4; i++){
    int gm = blockIdx.x * 128 + wm + i * 16 + quad * 4;
    #pragma unroll
    for (int j = 0; j < 4; j++){
      int ng = blockIdx.y * 128 + wn + j * 16 + l16;
      float bv = bias[ng];
      #pragma unroll
      for (int r = 0; r < 4; r++)
        out[(size_t)(gm + r) * 1024 + ng] = acc[i][j][r] + bv;
    }
  }
}

extern "C" void kernel_launch(void* const* d_in, const int* in_sizes, int n_in,
                              void* d_out, int out_size, void* d_ws, size_t ws_size,
                              hipStream_t stream) {
  const float* x    = (const float*)d_in[0];   // [4,2048,1024]
  const float* Wqkv = (const float*)d_in[1];   // [1024,3072]
  const float* bqkv = (const float*)d_in[2];   // [3072]
  const float* Wo   = (const float*)d_in[3];   // [1024,1024]
  const float* bo   = (const float*)d_in[4];   // [1024]
  float* out = (float*)d_out;

  char* p = (char*)d_ws;
  ushort* xb  = (ushort*)p;                         // 16 MB (x bf16, later reused as O)
  ushort* WqT = (ushort*)(p + 16777216);            // 6 MB
  ushort* WoT = (ushort*)(p + 16777216 + 6291456);  // 2 MB
  ushort* Qd  = (ushort*)(p + 25165824);            // 16 MB each
  ushort* Kd  = (ushort*)(p + 25165824 + 16777216);
  ushort* Vt  = (ushort*)(p + 25165824 + 33554432);
  ushort* Od  = xb;                                 // x dead after gemm_qkv

  cast_x_kernel<<<8192, 256, 0, stream>>>((const float4*)x, xb);
  transpose_cast_kernel<<<dim3(96, 32), dim3(32, 8), 0, stream>>>(Wqkv, WqT, 1024, 3072);
  transpose_cast_kernel<<<dim3(32, 32), dim3(32, 8), 0, stream>>>(Wo, WoT, 1024, 1024);
  gemm_qkv_kernel<<<dim3(64, 24), 256, 0, stream>>>(xb, WqT, bqkv, Qd, Kd, Vt);
  flash_attn_kernel<<<dim3(64, 16), 256, 0, stream>>>(Qd, Kd, Vt, Od);
  gemm_out_kernel<<<dim3(64, 8), 256, 0, stream>>>(Od, WoT, bo, out);
}

// Round 4
// 269.675 us; speedup vs baseline: 1.0080x; 1.0080x over previous
//
#include <hip/hip_runtime.h>
#include <hip/hip_bf16.h>

typedef __attribute__((ext_vector_type(8))) short bh8;
typedef __attribute__((ext_vector_type(4))) float f32x4;

#define GBL(p) (const __attribute__((address_space(1))) void*)(p)
#define LDSP(p) (__attribute__((address_space(3))) void*)(p)

__device__ __forceinline__ ushort f2bf(float f){
  union { float f; unsigned u; } v; v.f = f;
  unsigned u = v.u;
  return (ushort)((u + 0x7fffu + ((u >> 16) & 1u)) >> 16);
}

// ---------------- prologue: cast x to bf16 ----------------
__global__ __launch_bounds__(256) void cast_x_kernel(const float4* __restrict__ in,
                                                     ushort* __restrict__ out){
  int i = blockIdx.x * 256 + threadIdx.x;
  float4 v = in[i];
  ushort4 o;
  o.x = f2bf(v.x); o.y = f2bf(v.y); o.z = f2bf(v.z); o.w = f2bf(v.w);
  *(ushort4*)&out[(size_t)i * 4] = o;
}

// ---------------- prologue: transpose-cast W [R][C] fp32 -> [C][R] bf16 ----------------
__global__ __launch_bounds__(256) void transpose_cast_kernel(const float* __restrict__ in,
                                                             ushort* __restrict__ out,
                                                             int R, int C){
  __shared__ float tile[32][33];
  int bx = blockIdx.x * 32;
  int by = blockIdx.y * 32;
  int tx = threadIdx.x, ty = threadIdx.y;  // 32x8
  #pragma unroll
  for (int i = 0; i < 32; i += 8)
    tile[ty + i][tx] = in[(size_t)(by + ty + i) * C + bx + tx];
  __syncthreads();
  #pragma unroll
  for (int i = 0; i < 32; i += 8)
    out[(size_t)(bx + ty + i) * R + by + tx] = f2bf(tile[tx][ty + i]);
}

// ---------------- GEMM1: qkv = x @ Wqkv + b ----------------
// PROVEN structure: 128x128 tile, 256 thr, 4 blocks/CU (TLP hides staging).
// XOR-swizzled LDS: tile [128 rows][8 units of 16B], phys unit = row*8 + (cu^(row&7)).
__global__ __launch_bounds__(256) void gemm_qkv_kernel(
    const ushort* __restrict__ A,   // [8192][1024] bf16
    const ushort* __restrict__ Bt,  // [3072][1024] bf16 (W^T)
    const float* __restrict__ bias, // [3072]
    ushort* __restrict__ Qd, ushort* __restrict__ Kd, ushort* __restrict__ Vt)
{
  constexpr int K = 1024;
  __shared__ ushort sA[8192];   // [128][8 units] swizzled
  __shared__ ushort sB[8192];
  const int tid = threadIdx.x;
  const int lane = tid & 63, wave = tid >> 6;
  const int quad = lane >> 4, l16 = lane & 15;
  const int rx7 = l16 & 7;
  const int wm = (wave >> 1) * 64, wn = (wave & 1) * 64;
  const size_t aBase = (size_t)blockIdx.x * 128 * K;
  const size_t bBase = (size_t)blockIdx.y * 128 * K;
  f32x4 acc[4][4] = {};
  for (int k0 = 0; k0 < K; k0 += 64){
    #pragma unroll
    for (int c = 0; c < 4; c++){
      int u = c * 256 + tid;
      int row = u >> 3, cu = (u & 7) ^ (row & 7);
      __builtin_amdgcn_global_load_lds(GBL(A + aBase + (size_t)row * K + k0 + cu * 8),
                                       LDSP(&sA[u * 8]), 16, 0, 0);
      __builtin_amdgcn_global_load_lds(GBL(Bt + bBase + (size_t)row * K + k0 + cu * 8),
                                       LDSP(&sB[u * 8]), 16, 0, 0);
    }
    __syncthreads();
    #pragma unroll
    for (int ks = 0; ks < 2; ks++){
      bh8 af[4], bf[4];
      #pragma unroll
      for (int i = 0; i < 4; i++){
        int row = wm + i * 16 + l16;
        af[i] = *(const bh8*)&sA[row * 64 + (((ks * 4 + quad) ^ rx7) << 3)];
      }
      #pragma unroll
      for (int j = 0; j < 4; j++){
        int row = wn + j * 16 + l16;
        bf[j] = *(const bh8*)&sB[row * 64 + (((ks * 4 + quad) ^ rx7) << 3)];
      }
      #pragma unroll
      for (int i = 0; i < 4; i++)
        #pragma unroll
        for (int j = 0; j < 4; j++)
          acc[i][j] = __builtin_amdgcn_mfma_f32_16x16x32_bf16(af[i], bf[j], acc[i][j], 0, 0, 0);
    }
    __syncthreads();
  }
  const int whichBlk = (blockIdx.y * 128) >> 10;  // 0=Q 1=K 2=V (uniform per block)
  #pragma unroll
  for (int i = 0; i < 4; i++){
    int mg = blockIdx.x * 128 + wm + i * 16 + quad * 4;
    int bb = mg >> 11, t0 = mg & 2047;
    #pragma unroll
    for (int j = 0; j < 4; j++){
      int ng = blockIdx.y * 128 + wn + j * 16 + l16;
      float bv = bias[ng];
      int h = (ng >> 6) & 15;
      int dh = ng & 63;
      if (whichBlk == 2){
        ushort4 o;
        o.x = f2bf(acc[i][j][0] + bv);
        o.y = f2bf(acc[i][j][1] + bv);
        o.z = f2bf(acc[i][j][2] + bv);
        o.w = f2bf(acc[i][j][3] + bv);
        *(ushort4*)&Vt[((size_t)((bb * 16 + h) * 64 + dh)) * 2048 + t0] = o;
      } else {
        ushort* dst = (whichBlk == 0) ? Qd : Kd;
        // Q: fold 1/sqrt(64) * log2(e) so flash can use bare exp2
        float sc = (whichBlk == 0) ? 0.18033688f : 1.0f;
        #pragma unroll
        for (int r = 0; r < 4; r++)
          dst[((size_t)((bb * 16 + h) * 2048 + t0 + r) << 6) + dh] = f2bf((acc[i][j][r] + bv) * sc);
      }
    }
  }
}

// ---------------- flash attention v8 (causal, QK-skewed pipeline) ----------------
// Round-2 structure (sP LDS transpose path, proven 82.4us) + one-tile skew:
// QK(kt+1) MFMAs are issued BETWEEN the sP-write and the PV(kt) sP-read, so the
// sP write->read LDS round-trip and the softmax VALU chain overlap the MFMA pipe
// (T15 mechanism). K prefetch depth 2 -> 3 K slots (slot (kt+2)%3 last read at
// iter kt-2, two barriers back -> no DMA overwrite race); V stays 2-slot staged
// 1 ahead; sP per-wave (DS in-order per wave -> no barrier needed).
// 1 barrier/tile; its implicit vmcnt drain covers exactly K(kt+1),V(kt).
// LDS 48KB -> 3 blocks/CU.
__global__ __launch_bounds__(256, 3) void flash_attn_kernel(
    const ushort* __restrict__ Qd, const ushort* __restrict__ Kd,
    const ushort* __restrict__ Vt, ushort* __restrict__ Od)
{
  __shared__ ushort sK[3][4096];
  __shared__ ushort sV[2][4096];
  __shared__ ushort sP[4][1024];
  const int tid = threadIdx.x;
  const int lane = tid & 63, wave = tid >> 6;
  const int quad = lane >> 4, l16 = lane & 15;
  const int bh = blockIdx.x, pairI = blockIdx.y;
  const size_t base = (size_t)bh * (2048 * 64);
  const float SINIT = -7.2134752f;   // -5 * log2(e)

  const int p0 = tid, p1 = 256 + tid;
  const int r0 = p0 >> 3, c0 = (p0 & 7) ^ (r0 & 7);
  const int r1 = p1 >> 3, c1 = (p1 & 7) ^ (r1 & 7);
  const ushort* kp0 = Kd + base + r0 * 64 + c0 * 8;
  const ushort* kp1 = Kd + base + r1 * 64 + c1 * 8;
  const ushort* vp0 = Vt + base + (size_t)r0 * 2048 + c0 * 8;
  const ushort* vp1 = Vt + base + (size_t)r1 * 2048 + c1 * 8;

  const int b = bh >> 4, h = bh & 15;

  #pragma unroll 1
  for (int phase = 0; phase < 2; phase++){
    const int qt = phase ? pairI : (31 - pairI);
    const ushort* qrow = Qd + base + (size_t)(qt * 64 + wave * 16 + l16) * 64 + quad * 8;
    bh8 qf0 = *(const bh8*)qrow;
    bh8 qf1 = *(const bh8*)(qrow + 32);

    f32x4 Oacc[4] = {};
    float lpart[4] = {0.f, 0.f, 0.f, 0.f};

    __syncthreads();   // protect prior phase's LDS reads
    // prologue: K(0)->sK[0], V(0)->sV[0], K(1)->sK[1]
    __builtin_amdgcn_global_load_lds(GBL(kp0), LDSP(&sK[0][p0 * 8]), 16, 0, 0);
    __builtin_amdgcn_global_load_lds(GBL(kp1), LDSP(&sK[0][p1 * 8]), 16, 0, 0);
    __builtin_amdgcn_global_load_lds(GBL(vp0), LDSP(&sV[0][p0 * 8]), 16, 0, 0);
    __builtin_amdgcn_global_load_lds(GBL(vp1), LDSP(&sV[0][p1 * 8]), 16, 0, 0);
    __builtin_amdgcn_global_load_lds(GBL(kp0 + 4096), LDSP(&sK[1][p0 * 8]), 16, 0, 0);
    __builtin_amdgcn_global_load_lds(GBL(kp1 + 4096), LDSP(&sK[1][p1 * 8]), 16, 0, 0);
    __syncthreads();   // all prologue tiles resident

    // QK(0) -> S
    f32x4 S[4];
    #pragma unroll
    for (int j = 0; j < 4; j++) S[j] = (f32x4){SINIT, SINIT, SINIT, SINIT};
    __builtin_amdgcn_s_setprio(1);
    #pragma unroll
    for (int ks = 0; ks < 2; ks++){
      bh8 aq = ks ? qf1 : qf0;
      #pragma unroll
      for (int j = 0; j < 4; j++){
        int row = j * 16 + l16;
        int u = row * 8 + ((ks * 4 + quad) ^ (row & 7));
        bh8 bk = *(const bh8*)&sK[0][u * 8];
        S[j] = __builtin_amdgcn_mfma_f32_16x16x32_bf16(aq, bk, S[j], 0, 0, 0);
      }
    }
    __builtin_amdgcn_s_setprio(0);

    int slot_next = 1, slot_stage = 2;   // K slots: (kt+1)%3, (kt+2)%3
    #pragma unroll 1
    for (int kt = 0; kt <= qt; kt++){
      const int vb = kt & 1;
      __syncthreads();                   // K(kt+1) & V(kt) resident (issued iter kt-1/prologue)
      if (kt + 2 <= qt){
        __builtin_amdgcn_global_load_lds(GBL(kp0 + (kt + 2) * 4096), LDSP(&sK[slot_stage][p0 * 8]), 16, 0, 0);
        __builtin_amdgcn_global_load_lds(GBL(kp1 + (kt + 2) * 4096), LDSP(&sK[slot_stage][p1 * 8]), 16, 0, 0);
      }
      if (kt + 1 <= qt){
        __builtin_amdgcn_global_load_lds(GBL(vp0 + (kt + 1) * 64), LDSP(&sV[vb ^ 1][p0 * 8]), 16, 0, 0);
        __builtin_amdgcn_global_load_lds(GBL(vp1 + (kt + 1) * 64), LDSP(&sV[vb ^ 1][p1 * 8]), 16, 0, 0);
      }
      // ---- softmax of S(kt) (VALU) + sP write
      if (kt == qt){
        #pragma unroll
        for (int j = 0; j < 4; j++)
          #pragma unroll
          for (int r = 0; r < 4; r++){
            int relq = wave * 16 + quad * 4 + r;
            int relt = j * 16 + l16;
            if (relt > relq) S[j][r] = -1e30f;
          }
      }
      #pragma unroll
      for (int j = 0; j < 4; j++){
        float pv[4];
        #pragma unroll
        for (int r = 0; r < 4; r++){
          pv[r] = exp2f(S[j][r]);     // bare v_exp_f32
          lpart[r] += pv[r];
        }
        __hip_bfloat162 pk0 = __float22bfloat162_rn({pv[0], pv[1]});
        __hip_bfloat162 pk1 = __float22bfloat162_rn({pv[2], pv[3]});
        ushort2 w0 = *(ushort2*)&pk0, w1 = *(ushort2*)&pk1;
        ushort w[4] = {w0.x, w0.y, w1.x, w1.y};
        #pragma unroll
        for (int r = 0; r < 4; r++){
          int row = quad * 4 + r;
          int cu = 2 * j + (l16 >> 3);
          int phys = row * 8 + (cu ^ (row & 7));
          sP[wave][phys * 8 + (l16 & 7)] = w[r];
        }
      }
      // ---- QK(kt+1) (MFMA) — fills the sP write->read gap
      f32x4 Sn[4];
      if (kt < qt){
        #pragma unroll
        for (int j = 0; j < 4; j++) Sn[j] = (f32x4){SINIT, SINIT, SINIT, SINIT};
        __builtin_amdgcn_s_setprio(1);
        #pragma unroll
        for (int ks = 0; ks < 2; ks++){
          bh8 aq = ks ? qf1 : qf0;
          #pragma unroll
          for (int j = 0; j < 4; j++){
            int row = j * 16 + l16;
            int u = row * 8 + ((ks * 4 + quad) ^ (row & 7));
            bh8 bk = *(const bh8*)&sK[slot_next][u * 8];
            Sn[j] = __builtin_amdgcn_mfma_f32_16x16x32_bf16(aq, bk, Sn[j], 0, 0, 0);
          }
        }
        __builtin_amdgcn_s_setprio(0);
      }
      // ---- PV(kt)
      __builtin_amdgcn_s_setprio(1);
      #pragma unroll
      for (int ks = 0; ks < 2; ks++){
        int up = l16 * 8 + ((ks * 4 + quad) ^ (l16 & 7));
        bh8 ap = *(const bh8*)&sP[wave][up * 8];
        #pragma unroll
        for (int j = 0; j < 4; j++){
          int row = j * 16 + l16;
          int u = row * 8 + ((ks * 4 + quad) ^ (row & 7));
          bh8 bv = *(const bh8*)&sV[vb][u * 8];
          Oacc[j] = __builtin_amdgcn_mfma_f32_16x16x32_bf16(ap, bv, Oacc[j], 0, 0, 0);
        }
      }
      __builtin_amdgcn_s_setprio(0);
      if (kt < qt){
        #pragma unroll
        for (int j = 0; j < 4; j++) S[j] = Sn[j];
      }
      int t = slot_next;
      slot_next = slot_stage;
      slot_stage = (t + 0 == 0) ? 1 : ((slot_stage + 1 == 3) ? 0 : slot_stage + 1);
      slot_stage = (slot_next + 1 == 3) ? 0 : slot_next + 1;  // (kt+3)%3 successor
    }
    // ---- denominator + epilogue (round-2 exact)
    float lr[4];
    #pragma unroll
    for (int r = 0; r < 4; r++){
      float s = lpart[r];
      s += __shfl_xor(s, 1, 64);
      s += __shfl_xor(s, 2, 64);
      s += __shfl_xor(s, 4, 64);
      s += __shfl_xor(s, 8, 64);
      lr[r] = 1.0f / s;
    }
    #pragma unroll
    for (int j = 0; j < 4; j++)
      #pragma unroll
      for (int r = 0; r < 4; r++){
        int qg = qt * 64 + wave * 16 + quad * 4 + r;
        int dh = j * 16 + l16;
        Od[(size_t)(b * 2048 + qg) * 1024 + h * 64 + dh] = f2bf(Oacc[j][r] * lr[r]);
      }
  }
}

// ---------------- GEMM2: out = O @ Wo + b_o (fp32 out) ----------------
// 128x128 tile (mirrors proven gemm_qkv structure).
// Grid (64,8) = 512 blocks = 2 exact rounds, 4 blocks/CU; XOR-swizzled LDS.
__global__ __launch_bounds__(256) void gemm_out_kernel(
    const ushort* __restrict__ A,   // [8192][1024] bf16 (O)
    const ushort* __restrict__ Bt,  // [1024][1024] bf16 (Wo^T)
    const float* __restrict__ bias, // [1024]
    float* __restrict__ out)        // [8192][1024] fp32
{
  constexpr int K = 1024;
  __shared__ ushort sA[8192];   // [128][8] swizzled
  __shared__ ushort sB[8192];   // [128][8] swizzled
  const int tid = threadIdx.x;
  const int lane = tid & 63, wave = tid >> 6;
  const int quad = lane >> 4, l16 = lane & 15;
  const int rx7 = l16 & 7;
  const int wm = (wave >> 1) * 64, wn = (wave & 1) * 64;
  const size_t aBase = (size_t)blockIdx.x * 128 * K;
  const size_t bBase = (size_t)blockIdx.y * 128 * K;
  f32x4 acc[4][4] = {};
  for (int k0 = 0; k0 < K; k0 += 64){
    #pragma unroll
    for (int c = 0; c < 4; c++){
      int u = c * 256 + tid;
      int row = u >> 3, cu = (u & 7) ^ (row & 7);
      __builtin_amdgcn_global_load_lds(GBL(A + aBase + (size_t)row * K + k0 + cu * 8),
                                       LDSP(&sA[u * 8]), 16, 0, 0);
      __builtin_amdgcn_global_load_lds(GBL(Bt + bBase + (size_t)row * K + k0 + cu * 8),
                                       LDSP(&sB[u * 8]), 16, 0, 0);
    }
    __syncthreads();
    #pragma unroll
    for (int ks = 0; ks < 2; ks++){
      bh8 af[4], bf[4];
      #pragma unroll
      for (int i = 0; i < 4; i++){
        int row = wm + i * 16 + l16;
        af[i] = *(const bh8*)&sA[row * 64 + (((ks * 4 + quad) ^ rx7) << 3)];
      }
      #pragma unroll
      for (int j = 0; j < 4; j++){
        int row = wn + j * 16 + l16;
        bf[j] = *(const bh8*)&sB[row * 64 + (((ks * 4 + quad) ^ rx7) << 3)];
      }
      #pragma unroll
      for (int i = 0; i < 4; i++)
        #pragma unroll
        for (int j = 0; j < 4; j++)
          acc[i][j] = __builtin_amdgcn_mfma_f32_16x16x32_bf16(af[i], bf[j], acc[i][j], 0, 0, 0);
    }
    __syncthreads();
  }
  #pragma unroll
  for (int i = 0; i < 4; i++){
    int gm = blockIdx.x * 128 + wm + i * 16 + quad * 4;
    #pragma unroll
    for (int j = 0; j < 4; j++){
      int ng = blockIdx.y * 128 + wn + j * 16 + l16;
      float bv = bias[ng];
      #pragma unroll
      for (int r = 0; r < 4; r++)
        out[(size_t)(gm + r) * 1024 + ng] = acc[i][j][r] + bv;
    }
  }
}

extern "C" void kernel_launch(void* const* d_in, const int* in_sizes, int n_in,
                              void* d_out, int out_size, void* d_ws, size_t ws_size,
                              hipStream_t stream) {
  const float* x    = (const float*)d_in[0];   // [4,2048,1024]
  const float* Wqkv = (const float*)d_in[1];   // [1024,3072]
  const float* bqkv = (const float*)d_in[2];   // [3072]
  const float* Wo   = (const float*)d_in[3];   // [1024,1024]
  const float* bo   = (const float*)d_in[4];   // [1024]
  float* out = (float*)d_out;

  char* p = (char*)d_ws;
  ushort* xb  = (ushort*)p;                         // 16 MB (x bf16, later reused as O)
  ushort* WqT = (ushort*)(p + 16777216);            // 6 MB
  ushort* WoT = (ushort*)(p + 16777216 + 6291456);  // 2 MB
  ushort* Qd  = (ushort*)(p + 25165824);            // 16 MB each
  ushort* Kd  = (ushort*)(p + 25165824 + 16777216);
  ushort* Vt  = (ushort*)(p + 25165824 + 33554432);
  ushort* Od  = xb;                                 // x dead after gemm_qkv

  cast_x_kernel<<<8192, 256, 0, stream>>>((const float4*)x, xb);
  transpose_cast_kernel<<<dim3(96, 32), dim3(32, 8), 0, stream>>>(Wqkv, WqT, 1024, 3072);
  transpose_cast_kernel<<<dim3(32, 32), dim3(32, 8), 0, stream>>>(Wo, WoT, 1024, 1024);
  gemm_qkv_kernel<<<dim3(64, 24), 256, 0, stream>>>(xb, WqT, bqkv, Qd, Kd, Vt);
  flash_attn_kernel<<<dim3(64, 16), 256, 0, stream>>>(Qd, Kd, Vt, Od);
  gemm_out_kernel<<<dim3(64, 8), 256, 0, stream>>>(Od, WoT, bo, out);
}

// Round 5
// 262.583 us; speedup vs baseline: 1.0352x; 1.0270x over previous
//
#include <hip/hip_runtime.h>
#include <hip/hip_bf16.h>

typedef __attribute__((ext_vector_type(8))) short bh8;
typedef __attribute__((ext_vector_type(4))) float f32x4;

#define GBL(p) (const __attribute__((address_space(1))) void*)(p)
#define LDSP(p) (__attribute__((address_space(3))) void*)(p)

__device__ __forceinline__ ushort f2bf(float f){
  union { float f; unsigned u; } v; v.f = f;
  unsigned u = v.u;
  return (ushort)((u + 0x7fffu + ((u >> 16) & 1u)) >> 16);
}

// ---------------- prologue: cast x to bf16 ----------------
__global__ __launch_bounds__(256) void cast_x_kernel(const float4* __restrict__ in,
                                                     ushort* __restrict__ out){
  int i = blockIdx.x * 256 + threadIdx.x;
  float4 v = in[i];
  ushort4 o;
  o.x = f2bf(v.x); o.y = f2bf(v.y); o.z = f2bf(v.z); o.w = f2bf(v.w);
  *(ushort4*)&out[(size_t)i * 4] = o;
}

// ---------------- prologue: transpose-cast W [R][C] fp32 -> [C][R] bf16 ----------------
__global__ __launch_bounds__(256) void transpose_cast_kernel(const float* __restrict__ in,
                                                             ushort* __restrict__ out,
                                                             int R, int C){
  __shared__ float tile[32][33];
  int bx = blockIdx.x * 32;
  int by = blockIdx.y * 32;
  int tx = threadIdx.x, ty = threadIdx.y;  // 32x8
  #pragma unroll
  for (int i = 0; i < 32; i += 8)
    tile[ty + i][tx] = in[(size_t)(by + ty + i) * C + bx + tx];
  __syncthreads();
  #pragma unroll
  for (int i = 0; i < 32; i += 8)
    out[(size_t)(bx + ty + i) * R + by + tx] = f2bf(tile[tx][ty + i]);
}

// ---------------- GEMM1: qkv = x @ Wqkv + b ----------------
// 128x128 tile + 2-phase double-buffered pipeline (T3-min, race-free):
// per K-step (BK=32): issue next-tile DMA -> ds_read+MFMA resident tile ->
// vmcnt(0)+barrier. DMA overlaps the compute; LDS stays 32KB (2 bufs of 16KB)
// so 4 blocks/CU TLP is preserved on top of the in-wave overlap.
// Swizzle: phys unit = row*4 + (ku ^ ((row^(row>>2))&3)) -> 2-way banks (free).
__global__ __launch_bounds__(256, 4) void gemm_qkv_kernel(
    const ushort* __restrict__ A,   // [8192][1024] bf16
    const ushort* __restrict__ Bt,  // [3072][1024] bf16 (W^T)
    const float* __restrict__ bias, // [3072]
    ushort* __restrict__ Qd, ushort* __restrict__ Kd, ushort* __restrict__ Vt)
{
  constexpr int K = 1024;
  __shared__ ushort sA[2][4096];   // [buf][128 rows][4 units of 16B] swizzled
  __shared__ ushort sB[2][4096];
  const int tid = threadIdx.x;
  const int lane = tid & 63, wave = tid >> 6;
  const int quad = lane >> 4, l16 = lane & 15;
  const int wm = (wave >> 1) * 64, wn = (wave & 1) * 64;
  const size_t aBase = (size_t)blockIdx.x * 128 * K;
  const size_t bBase = (size_t)blockIdx.y * 128 * K;

  // staging geometry: units u = tid, 256+tid; row = u>>2; src col unit = (u&3)^swz(row)
  const int u0 = tid, u1 = 256 + tid;
  const int r0 = u0 >> 2, c0 = (u0 & 3) ^ ((r0 ^ (r0 >> 2)) & 3);
  const int r1 = u1 >> 2, c1 = (u1 & 3) ^ ((r1 ^ (r1 >> 2)) & 3);
  const ushort* a0 = A + aBase + (size_t)r0 * K + c0 * 8;
  const ushort* a1 = A + aBase + (size_t)r1 * K + c1 * 8;
  const ushort* b0 = Bt + bBase + (size_t)r0 * K + c0 * 8;
  const ushort* b1 = Bt + bBase + (size_t)r1 * K + c1 * 8;

  // frag read offsets (ushort index), loop-invariant
  int aoff[4], boff[4];
  #pragma unroll
  for (int i = 0; i < 4; i++){
    int ra = wm + i * 16 + l16;
    aoff[i] = (ra * 4 + (quad ^ ((ra ^ (ra >> 2)) & 3))) * 8;
    int rb = wn + i * 16 + l16;
    boff[i] = (rb * 4 + (quad ^ ((rb ^ (rb >> 2)) & 3))) * 8;
  }

  f32x4 acc[4][4] = {};
  // prologue: stage K-tile 0 into buf 0, full drain
  __builtin_amdgcn_global_load_lds(GBL(a0), LDSP(&sA[0][u0 * 8]), 16, 0, 0);
  __builtin_amdgcn_global_load_lds(GBL(a1), LDSP(&sA[0][u1 * 8]), 16, 0, 0);
  __builtin_amdgcn_global_load_lds(GBL(b0), LDSP(&sB[0][u0 * 8]), 16, 0, 0);
  __builtin_amdgcn_global_load_lds(GBL(b1), LDSP(&sB[0][u1 * 8]), 16, 0, 0);
  asm volatile("s_waitcnt vmcnt(0)" ::: "memory");
  __builtin_amdgcn_s_barrier();

  #pragma unroll 2
  for (int t = 0; t < 32; t++){
    const int cur = t & 1;
    if (t < 31){                      // issue NEXT tile's DMA first (overlaps compute)
      const int nb = cur ^ 1, ko = (t + 1) * 32;
      __builtin_amdgcn_global_load_lds(GBL(a0 + ko), LDSP(&sA[nb][u0 * 8]), 16, 0, 0);
      __builtin_amdgcn_global_load_lds(GBL(a1 + ko), LDSP(&sA[nb][u1 * 8]), 16, 0, 0);
      __builtin_amdgcn_global_load_lds(GBL(b0 + ko), LDSP(&sB[nb][u0 * 8]), 16, 0, 0);
      __builtin_amdgcn_global_load_lds(GBL(b1 + ko), LDSP(&sB[nb][u1 * 8]), 16, 0, 0);
    }
    bh8 af[4], bf[4];
    #pragma unroll
    for (int i = 0; i < 4; i++) af[i] = *(const bh8*)&sA[cur][aoff[i]];
    #pragma unroll
    for (int j = 0; j < 4; j++) bf[j] = *(const bh8*)&sB[cur][boff[j]];
    __builtin_amdgcn_s_setprio(1);
    #pragma unroll
    for (int i = 0; i < 4; i++)
      #pragma unroll
      for (int j = 0; j < 4; j++)
        acc[i][j] = __builtin_amdgcn_mfma_f32_16x16x32_bf16(af[i], bf[j], acc[i][j], 0, 0, 0);
    __builtin_amdgcn_s_setprio(0);
    asm volatile("s_waitcnt vmcnt(0)" ::: "memory");
    __builtin_amdgcn_s_barrier();
  }

  const int whichBlk = (blockIdx.y * 128) >> 10;  // 0=Q 1=K 2=V (uniform per block)
  #pragma unroll
  for (int i = 0; i < 4; i++){
    int mg = blockIdx.x * 128 + wm + i * 16 + quad * 4;
    int bb = mg >> 11, t0 = mg & 2047;
    #pragma unroll
    for (int j = 0; j < 4; j++){
      int ng = blockIdx.y * 128 + wn + j * 16 + l16;
      float bv = bias[ng];
      int h = (ng >> 6) & 15;
      int dh = ng & 63;
      if (whichBlk == 2){
        ushort4 o;
        o.x = f2bf(acc[i][j][0] + bv);
        o.y = f2bf(acc[i][j][1] + bv);
        o.z = f2bf(acc[i][j][2] + bv);
        o.w = f2bf(acc[i][j][3] + bv);
        *(ushort4*)&Vt[((size_t)((bb * 16 + h) * 64 + dh)) * 2048 + t0] = o;
      } else {
        ushort* dst = (whichBlk == 0) ? Qd : Kd;
        // Q: fold 1/sqrt(64) * log2(e) so flash can use bare exp2
        float sc = (whichBlk == 0) ? 0.18033688f : 1.0f;
        #pragma unroll
        for (int r = 0; r < 4; r++)
          dst[((size_t)((bb * 16 + h) * 2048 + t0 + r) << 6) + dh] = f2bf((acc[i][j][r] + bv) * sc);
      }
    }
  }
}

// ---------------- flash attention v6 (causal) — round-2 proven (82.4us) ----------------
// 64-row q-tiles, 16 pair-blocks per bh (qt in {31-p, p}: 33 iters uniform).
// Grid (64 bh, 16 p) -> XCD = bh%8 co-location. 4 blocks/CU (LDS 40KB).
// Softmax in exp2 space: Q pre-scaled by 0.125*log2e, S init -5*log2e.
// T5: s_setprio(1) around MFMA clusters.
__global__ __launch_bounds__(256, 4) void flash_attn_kernel(
    const ushort* __restrict__ Qd, const ushort* __restrict__ Kd,
    const ushort* __restrict__ Vt, ushort* __restrict__ Od)
{
  __shared__ ushort sK[2][4096];
  __shared__ ushort sV[2][4096];
  __shared__ ushort sP[4][1024];
  const int tid = threadIdx.x;
  const int lane = tid & 63, wave = tid >> 6;
  const int quad = lane >> 4, l16 = lane & 15;
  const int bh = blockIdx.x, pairI = blockIdx.y;
  const size_t base = (size_t)bh * (2048 * 64);
  const float SINIT = -7.2134752f;   // -5 * log2(e)

  const int p0 = tid, p1 = 256 + tid;
  const int r0 = p0 >> 3, c0 = (p0 & 7) ^ (r0 & 7);
  const int r1 = p1 >> 3, c1 = (p1 & 7) ^ (r1 & 7);
  const ushort* kp0 = Kd + base + r0 * 64 + c0 * 8;
  const ushort* kp1 = Kd + base + r1 * 64 + c1 * 8;
  const ushort* vp0 = Vt + base + (size_t)r0 * 2048 + c0 * 8;
  const ushort* vp1 = Vt + base + (size_t)r1 * 2048 + c1 * 8;

  const int b = bh >> 4, h = bh & 15;

  #pragma unroll 1
  for (int phase = 0; phase < 2; phase++){
    const int qt = phase ? pairI : (31 - pairI);
    const ushort* qrow = Qd + base + (size_t)(qt * 64 + wave * 16 + l16) * 64 + quad * 8;
    bh8 qf0 = *(const bh8*)qrow;
    bh8 qf1 = *(const bh8*)(qrow + 32);

    f32x4 Oacc[4] = {};
    float lpart[4] = {0.f, 0.f, 0.f, 0.f};

    __syncthreads();
    __builtin_amdgcn_global_load_lds(GBL(kp0), LDSP(&sK[0][p0 * 8]), 16, 0, 0);
    __builtin_amdgcn_global_load_lds(GBL(kp1), LDSP(&sK[0][p1 * 8]), 16, 0, 0);
    __builtin_amdgcn_global_load_lds(GBL(vp0), LDSP(&sV[0][p0 * 8]), 16, 0, 0);
    __builtin_amdgcn_global_load_lds(GBL(vp1), LDSP(&sV[0][p1 * 8]), 16, 0, 0);

    #pragma unroll 1
    for (int kt = 0; kt <= qt; kt++){
      const int buf = kt & 1;
      __syncthreads();
      if (kt < qt){
        const int nb = buf ^ 1;
        __builtin_amdgcn_global_load_lds(GBL(kp0 + (kt + 1) * 4096), LDSP(&sK[nb][p0 * 8]), 16, 0, 0);
        __builtin_amdgcn_global_load_lds(GBL(kp1 + (kt + 1) * 4096), LDSP(&sK[nb][p1 * 8]), 16, 0, 0);
        __builtin_amdgcn_global_load_lds(GBL(vp0 + (kt + 1) * 64),   LDSP(&sV[nb][p0 * 8]), 16, 0, 0);
        __builtin_amdgcn_global_load_lds(GBL(vp1 + (kt + 1) * 64),   LDSP(&sV[nb][p1 * 8]), 16, 0, 0);
      }
      f32x4 S[4];
      #pragma unroll
      for (int j = 0; j < 4; j++) S[j] = (f32x4){SINIT, SINIT, SINIT, SINIT};
      __builtin_amdgcn_s_setprio(1);
      #pragma unroll
      for (int ks = 0; ks < 2; ks++){
        bh8 aq = ks ? qf1 : qf0;
        #pragma unroll
        for (int j = 0; j < 4; j++){
          int row = j * 16 + l16;
          int u = row * 8 + ((ks * 4 + quad) ^ (row & 7));
          bh8 bk = *(const bh8*)&sK[buf][u * 8];
          S[j] = __builtin_amdgcn_mfma_f32_16x16x32_bf16(aq, bk, S[j], 0, 0, 0);
        }
      }
      __builtin_amdgcn_s_setprio(0);
      if (kt == qt){
        #pragma unroll
        for (int j = 0; j < 4; j++)
          #pragma unroll
          for (int r = 0; r < 4; r++){
            int relq = wave * 16 + quad * 4 + r;
            int relt = j * 16 + l16;
            if (relt > relq) S[j][r] = -1e30f;
          }
      }
      #pragma unroll
      for (int j = 0; j < 4; j++){
        float pv[4];
        #pragma unroll
        for (int r = 0; r < 4; r++){
          pv[r] = exp2f(S[j][r]);     // bare v_exp_f32
          lpart[r] += pv[r];
        }
        __hip_bfloat162 pk0 = __float22bfloat162_rn({pv[0], pv[1]});
        __hip_bfloat162 pk1 = __float22bfloat162_rn({pv[2], pv[3]});
        ushort2 w0 = *(ushort2*)&pk0, w1 = *(ushort2*)&pk1;
        ushort w[4] = {w0.x, w0.y, w1.x, w1.y};
        #pragma unroll
        for (int r = 0; r < 4; r++){
          int row = quad * 4 + r;
          int cu = 2 * j + (l16 >> 3);
          int phys = row * 8 + (cu ^ (row & 7));
          sP[wave][phys * 8 + (l16 & 7)] = w[r];
        }
      }
      __builtin_amdgcn_s_setprio(1);
      #pragma unroll
      for (int ks = 0; ks < 2; ks++){
        int up = l16 * 8 + ((ks * 4 + quad) ^ (l16 & 7));
        bh8 ap = *(const bh8*)&sP[wave][up * 8];
        #pragma unroll
        for (int j = 0; j < 4; j++){
          int row = j * 16 + l16;
          int u = row * 8 + ((ks * 4 + quad) ^ (row & 7));
          bh8 bv = *(const bh8*)&sV[buf][u * 8];
          Oacc[j] = __builtin_amdgcn_mfma_f32_16x16x32_bf16(ap, bv, Oacc[j], 0, 0, 0);
        }
      }
      __builtin_amdgcn_s_setprio(0);
    }
    float lr[4];
    #pragma unroll
    for (int r = 0; r < 4; r++){
      float s = lpart[r];
      s += __shfl_xor(s, 1, 64);
      s += __shfl_xor(s, 2, 64);
      s += __shfl_xor(s, 4, 64);
      s += __shfl_xor(s, 8, 64);
      lr[r] = 1.0f / s;
    }
    #pragma unroll
    for (int j = 0; j < 4; j++)
      #pragma unroll
      for (int r = 0; r < 4; r++){
        int qg = qt * 64 + wave * 16 + quad * 4 + r;
        int dh = j * 16 + l16;
        Od[(size_t)(b * 2048 + qg) * 1024 + h * 64 + dh] = f2bf(Oacc[j][r] * lr[r]);
      }
  }
}

// ---------------- GEMM2: out = O @ Wo + b_o (fp32 out) ----------------
// Same 2-phase BK=32 double-buffered template as gemm_qkv. 128x128 tile,
// grid (64,8) = 512 blocks = 2 exact rounds, 4 blocks/CU.
__global__ __launch_bounds__(256, 4) void gemm_out_kernel(
    const ushort* __restrict__ A,   // [8192][1024] bf16 (O)
    const ushort* __restrict__ Bt,  // [1024][1024] bf16 (Wo^T)
    const float* __restrict__ bias, // [1024]
    float* __restrict__ out)        // [8192][1024] fp32
{
  constexpr int K = 1024;
  __shared__ ushort sA[2][4096];
  __shared__ ushort sB[2][4096];
  const int tid = threadIdx.x;
  const int lane = tid & 63, wave = tid >> 6;
  const int quad = lane >> 4, l16 = lane & 15;
  const int wm = (wave >> 1) * 64, wn = (wave & 1) * 64;
  const size_t aBase = (size_t)blockIdx.x * 128 * K;
  const size_t bBase = (size_t)blockIdx.y * 128 * K;

  const int u0 = tid, u1 = 256 + tid;
  const int r0 = u0 >> 2, c0 = (u0 & 3) ^ ((r0 ^ (r0 >> 2)) & 3);
  const int r1 = u1 >> 2, c1 = (u1 & 3) ^ ((r1 ^ (r1 >> 2)) & 3);
  const ushort* a0 = A + aBase + (size_t)r0 * K + c0 * 8;
  const ushort* a1 = A + aBase + (size_t)r1 * K + c1 * 8;
  const ushort* b0 = Bt + bBase + (size_t)r0 * K + c0 * 8;
  const ushort* b1 = Bt + bBase + (size_t)r1 * K + c1 * 8;

  int aoff[4], boff[4];
  #pragma unroll
  for (int i = 0; i < 4; i++){
    int ra = wm + i * 16 + l16;
    aoff[i] = (ra * 4 + (quad ^ ((ra ^ (ra >> 2)) & 3))) * 8;
    int rb = wn + i * 16 + l16;
    boff[i] = (rb * 4 + (quad ^ ((rb ^ (rb >> 2)) & 3))) * 8;
  }

  f32x4 acc[4][4] = {};
  __builtin_amdgcn_global_load_lds(GBL(a0), LDSP(&sA[0][u0 * 8]), 16, 0, 0);
  __builtin_amdgcn_global_load_lds(GBL(a1), LDSP(&sA[0][u1 * 8]), 16, 0, 0);
  __builtin_amdgcn_global_load_lds(GBL(b0), LDSP(&sB[0][u0 * 8]), 16, 0, 0);
  __builtin_amdgcn_global_load_lds(GBL(b1), LDSP(&sB[0][u1 * 8]), 16, 0, 0);
  asm volatile("s_waitcnt vmcnt(0)" ::: "memory");
  __builtin_amdgcn_s_barrier();

  #pragma unroll 2
  for (int t = 0; t < 32; t++){
    const int cur = t & 1;
    if (t < 31){
      const int nb = cur ^ 1, ko = (t + 1) * 32;
      __builtin_amdgcn_global_load_lds(GBL(a0 + ko), LDSP(&sA[nb][u0 * 8]), 16, 0, 0);
      __builtin_amdgcn_global_load_lds(GBL(a1 + ko), LDSP(&sA[nb][u1 * 8]), 16, 0, 0);
      __builtin_amdgcn_global_load_lds(GBL(b0 + ko), LDSP(&sB[nb][u0 * 8]), 16, 0, 0);
      __builtin_amdgcn_global_load_lds(GBL(b1 + ko), LDSP(&sB[nb][u1 * 8]), 16, 0, 0);
    }
    bh8 af[4], bf[4];
    #pragma unroll
    for (int i = 0; i < 4; i++) af[i] = *(const bh8*)&sA[cur][aoff[i]];
    #pragma unroll
    for (int j = 0; j < 4; j++) bf[j] = *(const bh8*)&sB[cur][boff[j]];
    __builtin_amdgcn_s_setprio(1);
    #pragma unroll
    for (int i = 0; i < 4; i++)
      #pragma unroll
      for (int j = 0; j < 4; j++)
        acc[i][j] = __builtin_amdgcn_mfma_f32_16x16x32_bf16(af[i], bf[j], acc[i][j], 0, 0, 0);
    __builtin_amdgcn_s_setprio(0);
    asm volatile("s_waitcnt vmcnt(0)" ::: "memory");
    __builtin_amdgcn_s_barrier();
  }

  #pragma unroll
  for (int i = 0; i < 4; i++){
    int gm = blockIdx.x * 128 + wm + i * 16 + quad * 4;
    #pragma unroll
    for (int j = 0; j < 4; j++){
      int ng = blockIdx.y * 128 + wn + j * 16 + l16;
      float bv = bias[ng];
      #pragma unroll
      for (int r = 0; r < 4; r++)
        out[(size_t)(gm + r) * 1024 + ng] = acc[i][j][r] + bv;
    }
  }
}

extern "C" void kernel_launch(void* const* d_in, const int* in_sizes, int n_in,
                              void* d_out, int out_size, void* d_ws, size_t ws_size,
                              hipStream_t stream) {
  const float* x    = (const float*)d_in[0];   // [4,2048,1024]
  const float* Wqkv = (const float*)d_in[1];   // [1024,3072]
  const float* bqkv = (const float*)d_in[2];   // [3072]
  const float* Wo   = (const float*)d_in[3];   // [1024,1024]
  const float* bo   = (const float*)d_in[4];   // [1024]
  float* out = (float*)d_out;

  char* p = (char*)d_ws;
  ushort* xb  = (ushort*)p;                         // 16 MB (x bf16, later reused as O)
  ushort* WqT = (ushort*)(p + 16777216);            // 6 MB
  ushort* WoT = (ushort*)(p + 16777216 + 6291456);  // 2 MB
  ushort* Qd  = (ushort*)(p + 25165824);            // 16 MB each
  ushort* Kd  = (ushort*)(p + 25165824 + 16777216);
  ushort* Vt  = (ushort*)(p + 25165824 + 33554432);
  ushort* Od  = xb;                                 // x dead after gemm_qkv

  cast_x_kernel<<<8192, 256, 0, stream>>>((const float4*)x, xb);
  transpose_cast_kernel<<<dim3(96, 32), dim3(32, 8), 0, stream>>>(Wqkv, WqT, 1024, 3072);
  transpose_cast_kernel<<<dim3(32, 32), dim3(32, 8), 0, stream>>>(Wo, WoT, 1024, 1024);
  gemm_qkv_kernel<<<dim3(64, 24), 256, 0, stream>>>(xb, WqT, bqkv, Qd, Kd, Vt);
  flash_attn_kernel<<<dim3(64, 16), 256, 0, stream>>>(Qd, Kd, Vt, Od);
  gemm_out_kernel<<<dim3(64, 8), 256, 0, stream>>>(Od, WoT, bo, out);
}

// Round 6
// 252.544 us; speedup vs baseline: 1.0764x; 1.0398x over previous
//
#include <hip/hip_runtime.h>
#include <hip/hip_bf16.h>

typedef __attribute__((ext_vector_type(8))) short bh8;
typedef __attribute__((ext_vector_type(4))) float f32x4;

#define GBL(p) (const __attribute__((address_space(1))) void*)(p)
#define LDSP(p) (__attribute__((address_space(3))) void*)(p)

__device__ __forceinline__ ushort f2bf(float f){
  union { float f; unsigned u; } v; v.f = f;
  unsigned u = v.u;
  return (ushort)((u + 0x7fffu + ((u >> 16) & 1u)) >> 16);
}

// ---------------- prologue: cast x to bf16 ----------------
__global__ __launch_bounds__(256) void cast_x_kernel(const float4* __restrict__ in,
                                                     ushort* __restrict__ out){
  int i = blockIdx.x * 256 + threadIdx.x;
  float4 v = in[i];
  ushort4 o;
  o.x = f2bf(v.x); o.y = f2bf(v.y); o.z = f2bf(v.z); o.w = f2bf(v.w);
  *(ushort4*)&out[(size_t)i * 4] = o;
}

// ---------------- prologue: transpose-cast W [R][C] fp32 -> [C][R] bf16 ----------------
__global__ __launch_bounds__(256) void transpose_cast_kernel(const float* __restrict__ in,
                                                             ushort* __restrict__ out,
                                                             int R, int C){
  __shared__ float tile[32][33];
  int bx = blockIdx.x * 32;
  int by = blockIdx.y * 32;
  int tx = threadIdx.x, ty = threadIdx.y;  // 32x8
  #pragma unroll
  for (int i = 0; i < 32; i += 8)
    tile[ty + i][tx] = in[(size_t)(by + ty + i) * C + bx + tx];
  __syncthreads();
  #pragma unroll
  for (int i = 0; i < 32; i += 8)
    out[(size_t)(bx + ty + i) * R + by + tx] = f2bf(tile[tx][ty + i]);
}

// ---------------- GEMM1: qkv = x @ Wqkv + b ----------------
// 128x128 tile + 2-phase double-buffered pipeline (T3-min, race-free):
// per K-step (BK=32): issue next-tile DMA -> ds_read+MFMA resident tile ->
// vmcnt(0)+barrier. DMA overlaps the compute; LDS stays 32KB (2 bufs of 16KB)
// so 4 blocks/CU TLP is preserved on top of the in-wave overlap.
// Swizzle: phys unit = row*4 + (ku ^ ((row^(row>>2))&3)) -> 2-way banks (free).
__global__ __launch_bounds__(256, 4) void gemm_qkv_kernel(
    const ushort* __restrict__ A,   // [8192][1024] bf16
    const ushort* __restrict__ Bt,  // [3072][1024] bf16 (W^T)
    const float* __restrict__ bias, // [3072]
    ushort* __restrict__ Qd, ushort* __restrict__ Kd, ushort* __restrict__ Vt)
{
  constexpr int K = 1024;
  __shared__ ushort sA[2][4096];   // [buf][128 rows][4 units of 16B] swizzled
  __shared__ ushort sB[2][4096];
  const int tid = threadIdx.x;
  const int lane = tid & 63, wave = tid >> 6;
  const int quad = lane >> 4, l16 = lane & 15;
  const int wm = (wave >> 1) * 64, wn = (wave & 1) * 64;
  const size_t aBase = (size_t)blockIdx.x * 128 * K;
  const size_t bBase = (size_t)blockIdx.y * 128 * K;

  const int u0 = tid, u1 = 256 + tid;
  const int r0 = u0 >> 2, c0 = (u0 & 3) ^ ((r0 ^ (r0 >> 2)) & 3);
  const int r1 = u1 >> 2, c1 = (u1 & 3) ^ ((r1 ^ (r1 >> 2)) & 3);
  const ushort* a0 = A + aBase + (size_t)r0 * K + c0 * 8;
  const ushort* a1 = A + aBase + (size_t)r1 * K + c1 * 8;
  const ushort* b0 = Bt + bBase + (size_t)r0 * K + c0 * 8;
  const ushort* b1 = Bt + bBase + (size_t)r1 * K + c1 * 8;

  int aoff[4], boff[4];
  #pragma unroll
  for (int i = 0; i < 4; i++){
    int ra = wm + i * 16 + l16;
    aoff[i] = (ra * 4 + (quad ^ ((ra ^ (ra >> 2)) & 3))) * 8;
    int rb = wn + i * 16 + l16;
    boff[i] = (rb * 4 + (quad ^ ((rb ^ (rb >> 2)) & 3))) * 8;
  }

  f32x4 acc[4][4] = {};
  __builtin_amdgcn_global_load_lds(GBL(a0), LDSP(&sA[0][u0 * 8]), 16, 0, 0);
  __builtin_amdgcn_global_load_lds(GBL(a1), LDSP(&sA[0][u1 * 8]), 16, 0, 0);
  __builtin_amdgcn_global_load_lds(GBL(b0), LDSP(&sB[0][u0 * 8]), 16, 0, 0);
  __builtin_amdgcn_global_load_lds(GBL(b1), LDSP(&sB[0][u1 * 8]), 16, 0, 0);
  asm volatile("s_waitcnt vmcnt(0)" ::: "memory");
  __builtin_amdgcn_s_barrier();

  #pragma unroll 2
  for (int t = 0; t < 32; t++){
    const int cur = t & 1;
    if (t < 31){                      // issue NEXT tile's DMA first (overlaps compute)
      const int nb = cur ^ 1, ko = (t + 1) * 32;
      __builtin_amdgcn_global_load_lds(GBL(a0 + ko), LDSP(&sA[nb][u0 * 8]), 16, 0, 0);
      __builtin_amdgcn_global_load_lds(GBL(a1 + ko), LDSP(&sA[nb][u1 * 8]), 16, 0, 0);
      __builtin_amdgcn_global_load_lds(GBL(b0 + ko), LDSP(&sB[nb][u0 * 8]), 16, 0, 0);
      __builtin_amdgcn_global_load_lds(GBL(b1 + ko), LDSP(&sB[nb][u1 * 8]), 16, 0, 0);
    }
    bh8 af[4], bf[4];
    #pragma unroll
    for (int i = 0; i < 4; i++) af[i] = *(const bh8*)&sA[cur][aoff[i]];
    #pragma unroll
    for (int j = 0; j < 4; j++) bf[j] = *(const bh8*)&sB[cur][boff[j]];
    __builtin_amdgcn_s_setprio(1);
    #pragma unroll
    for (int i = 0; i < 4; i++)
      #pragma unroll
      for (int j = 0; j < 4; j++)
        acc[i][j] = __builtin_amdgcn_mfma_f32_16x16x32_bf16(af[i], bf[j], acc[i][j], 0, 0, 0);
    __builtin_amdgcn_s_setprio(0);
    asm volatile("s_waitcnt vmcnt(0)" ::: "memory");
    __builtin_amdgcn_s_barrier();
  }

  const int whichBlk = (blockIdx.y * 128) >> 10;  // 0=Q 1=K 2=V (uniform per block)
  #pragma unroll
  for (int i = 0; i < 4; i++){
    int mg = blockIdx.x * 128 + wm + i * 16 + quad * 4;
    int bb = mg >> 11, t0 = mg & 2047;
    #pragma unroll
    for (int j = 0; j < 4; j++){
      int ng = blockIdx.y * 128 + wn + j * 16 + l16;
      float bv = bias[ng];
      int h = (ng >> 6) & 15;
      int dh = ng & 63;
      if (whichBlk == 2){
        ushort4 o;
        o.x = f2bf(acc[i][j][0] + bv);
        o.y = f2bf(acc[i][j][1] + bv);
        o.z = f2bf(acc[i][j][2] + bv);
        o.w = f2bf(acc[i][j][3] + bv);
        *(ushort4*)&Vt[((size_t)((bb * 16 + h) * 64 + dh)) * 2048 + t0] = o;
      } else {
        ushort* dst = (whichBlk == 0) ? Qd : Kd;
        // Q: fold 1/sqrt(64) * log2(e) so flash can use bare exp2
        float sc = (whichBlk == 0) ? 0.18033688f : 1.0f;
        #pragma unroll
        for (int r = 0; r < 4; r++)
          dst[((size_t)((bb * 16 + h) * 2048 + t0 + r) << 6) + dh] = f2bf((acc[i][j][r] + bv) * sc);
      }
    }
  }
}

// ---------------- flash attention v9 (causal, swapped-QK + vectorized sP) ----------------
// Round-2 proven schedule (2 barriers/tile equivalent, 4 blocks/CU, sP transpose),
// with QK^T swapped: S^T = mfma(A=K, B=Q) -> lane holds 4 CONSECUTIVE t values
// (t = j*16+quad*4+r) at fixed q = l16.  Effects, all inside the proven structure:
//  - sP write: one ushort4 ds_write_b64 per j (4/tile) replaces 16 scalar b16 writes
//    (cu = 2*j+(quad>>1), elem off = (quad&1)*4; phys unit = l16*8 + (cu^(l16&7)) --
//    exactly the layout PV's unchanged b128 read expects)
//  - mask + row-sum are lane-local (scalar lsum); denominator redistributed to the
//    C-layout lanes once per phase (2 shfl_xor + 4 shfl + 4 rcp)
// PV, prefetch, barriers, epilogue identical to round-2.
__global__ __launch_bounds__(256, 4) void flash_attn_kernel(
    const ushort* __restrict__ Qd, const ushort* __restrict__ Kd,
    const ushort* __restrict__ Vt, ushort* __restrict__ Od)
{
  __shared__ ushort sK[2][4096];
  __shared__ ushort sV[2][4096];
  __shared__ ushort sP[4][1024];
  const int tid = threadIdx.x;
  const int lane = tid & 63, wave = tid >> 6;
  const int quad = lane >> 4, l16 = lane & 15;
  const int bh = blockIdx.x, pairI = blockIdx.y;
  const size_t base = (size_t)bh * (2048 * 64);
  const float SINIT = -7.2134752f;   // -5 * log2(e)

  const int p0 = tid, p1 = 256 + tid;
  const int r0 = p0 >> 3, c0 = (p0 & 7) ^ (r0 & 7);
  const int r1 = p1 >> 3, c1 = (p1 & 7) ^ (r1 & 7);
  const ushort* kp0 = Kd + base + r0 * 64 + c0 * 8;
  const ushort* kp1 = Kd + base + r1 * 64 + c1 * 8;
  const ushort* vp0 = Vt + base + (size_t)r0 * 2048 + c0 * 8;
  const ushort* vp1 = Vt + base + (size_t)r1 * 2048 + c1 * 8;

  const int b = bh >> 4, h = bh & 15;

  // sP write offsets (ushort index into sP[wave]), loop-invariant: per j one ushort4
  int poff[4];
  #pragma unroll
  for (int j = 0; j < 4; j++){
    int cu = 2 * j + (quad >> 1);
    poff[j] = (l16 * 8 + (cu ^ (l16 & 7))) * 8 + (quad & 1) * 4;
  }

  #pragma unroll 1
  for (int phase = 0; phase < 2; phase++){
    const int qt = phase ? pairI : (31 - pairI);
    const ushort* qrow = Qd + base + (size_t)(qt * 64 + wave * 16 + l16) * 64 + quad * 8;
    bh8 qf0 = *(const bh8*)qrow;
    bh8 qf1 = *(const bh8*)(qrow + 32);

    f32x4 Oacc[4] = {};
    float lsum = 0.f;

    __syncthreads();
    __builtin_amdgcn_global_load_lds(GBL(kp0), LDSP(&sK[0][p0 * 8]), 16, 0, 0);
    __builtin_amdgcn_global_load_lds(GBL(kp1), LDSP(&sK[0][p1 * 8]), 16, 0, 0);
    __builtin_amdgcn_global_load_lds(GBL(vp0), LDSP(&sV[0][p0 * 8]), 16, 0, 0);
    __builtin_amdgcn_global_load_lds(GBL(vp1), LDSP(&sV[0][p1 * 8]), 16, 0, 0);

    #pragma unroll 1
    for (int kt = 0; kt <= qt; kt++){
      const int buf = kt & 1;
      __syncthreads();
      if (kt < qt){
        const int nb = buf ^ 1;
        __builtin_amdgcn_global_load_lds(GBL(kp0 + (kt + 1) * 4096), LDSP(&sK[nb][p0 * 8]), 16, 0, 0);
        __builtin_amdgcn_global_load_lds(GBL(kp1 + (kt + 1) * 4096), LDSP(&sK[nb][p1 * 8]), 16, 0, 0);
        __builtin_amdgcn_global_load_lds(GBL(vp0 + (kt + 1) * 64),   LDSP(&sV[nb][p0 * 8]), 16, 0, 0);
        __builtin_amdgcn_global_load_lds(GBL(vp1 + (kt + 1) * 64),   LDSP(&sV[nb][p1 * 8]), 16, 0, 0);
      }
      // ---- QK^T swapped (round-3 verified): lane holds t = j*16+quad*4+r at q = l16
      f32x4 S[4];
      #pragma unroll
      for (int j = 0; j < 4; j++) S[j] = (f32x4){SINIT, SINIT, SINIT, SINIT};
      __builtin_amdgcn_s_setprio(1);
      #pragma unroll
      for (int ks = 0; ks < 2; ks++){
        bh8 aq = ks ? qf1 : qf0;
        #pragma unroll
        for (int j = 0; j < 4; j++){
          int row = j * 16 + l16;
          int u = row * 8 + ((ks * 4 + quad) ^ (row & 7));
          bh8 bk = *(const bh8*)&sK[buf][u * 8];
          S[j] = __builtin_amdgcn_mfma_f32_16x16x32_bf16(bk, aq, S[j], 0, 0, 0);
        }
      }
      __builtin_amdgcn_s_setprio(0);
      if (kt == qt){
        const int relq = wave * 16 + l16;
        #pragma unroll
        for (int j = 0; j < 4; j++)
          #pragma unroll
          for (int r = 0; r < 4; r++){
            int relt = j * 16 + quad * 4 + r;
            if (relt > relq) S[j][r] = -1e30f;
          }
      }
      // ---- exp2 + lane-local sum + ONE ushort4 sP write per j
      #pragma unroll
      for (int j = 0; j < 4; j++){
        float pv[4];
        #pragma unroll
        for (int r = 0; r < 4; r++){
          pv[r] = exp2f(S[j][r]);     // bare v_exp_f32
          lsum += pv[r];
        }
        __hip_bfloat162 pk0 = __float22bfloat162_rn({pv[0], pv[1]});
        __hip_bfloat162 pk1 = __float22bfloat162_rn({pv[2], pv[3]});
        ushort2 w0 = *(ushort2*)&pk0, w1 = *(ushort2*)&pk1;
        ushort4 o4; o4.x = w0.x; o4.y = w0.y; o4.z = w1.x; o4.w = w1.y;
        *(ushort4*)&sP[wave][poff[j]] = o4;
      }
      // ---- PV (unchanged)
      __builtin_amdgcn_s_setprio(1);
      #pragma unroll
      for (int ks = 0; ks < 2; ks++){
        int up = l16 * 8 + ((ks * 4 + quad) ^ (l16 & 7));
        bh8 ap = *(const bh8*)&sP[wave][up * 8];
        #pragma unroll
        for (int j = 0; j < 4; j++){
          int row = j * 16 + l16;
          int u = row * 8 + ((ks * 4 + quad) ^ (row & 7));
          bh8 bv = *(const bh8*)&sV[buf][u * 8];
          Oacc[j] = __builtin_amdgcn_mfma_f32_16x16x32_bf16(ap, bv, Oacc[j], 0, 0, 0);
        }
      }
      __builtin_amdgcn_s_setprio(0);
    }
    // ---- denominator: lane-local -> full row sum -> redistribute to C-layout lanes
    float s = lsum;
    s += __shfl_xor(s, 16, 64);
    s += __shfl_xor(s, 32, 64);
    float lr[4];
    #pragma unroll
    for (int r = 0; r < 4; r++)
      lr[r] = 1.0f / __shfl(s, quad * 4 + r, 64);
    #pragma unroll
    for (int j = 0; j < 4; j++)
      #pragma unroll
      for (int r = 0; r < 4; r++){
        int qg = qt * 64 + wave * 16 + quad * 4 + r;
        int dh = j * 16 + l16;
        Od[(size_t)(b * 2048 + qg) * 1024 + h * 64 + dh] = f2bf(Oacc[j][r] * lr[r]);
      }
  }
}

// ---------------- GEMM2: out = O @ Wo + b_o (fp32 out) ----------------
// Same 2-phase BK=32 double-buffered template as gemm_qkv. 128x128 tile,
// grid (64,8) = 512 blocks = 2 exact rounds, 4 blocks/CU.
__global__ __launch_bounds__(256, 4) void gemm_out_kernel(
    const ushort* __restrict__ A,   // [8192][1024] bf16 (O)
    const ushort* __restrict__ Bt,  // [1024][1024] bf16 (Wo^T)
    const float* __restrict__ bias, // [1024]
    float* __restrict__ out)        // [8192][1024] fp32
{
  constexpr int K = 1024;
  __shared__ ushort sA[2][4096];
  __shared__ ushort sB[2][4096];
  const int tid = threadIdx.x;
  const int lane = tid & 63, wave = tid >> 6;
  const int quad = lane >> 4, l16 = lane & 15;
  const int wm = (wave >> 1) * 64, wn = (wave & 1) * 64;
  const size_t aBase = (size_t)blockIdx.x * 128 * K;
  const size_t bBase = (size_t)blockIdx.y * 128 * K;

  const int u0 = tid, u1 = 256 + tid;
  const int r0 = u0 >> 2, c0 = (u0 & 3) ^ ((r0 ^ (r0 >> 2)) & 3);
  const int r1 = u1 >> 2, c1 = (u1 & 3) ^ ((r1 ^ (r1 >> 2)) & 3);
  const ushort* a0 = A + aBase + (size_t)r0 * K + c0 * 8;
  const ushort* a1 = A + aBase + (size_t)r1 * K + c1 * 8;
  const ushort* b0 = Bt + bBase + (size_t)r0 * K + c0 * 8;
  const ushort* b1 = Bt + bBase + (size_t)r1 * K + c1 * 8;

  int aoff[4], boff[4];
  #pragma unroll
  for (int i = 0; i < 4; i++){
    int ra = wm + i * 16 + l16;
    aoff[i] = (ra * 4 + (quad ^ ((ra ^ (ra >> 2)) & 3))) * 8;
    int rb = wn + i * 16 + l16;
    boff[i] = (rb * 4 + (quad ^ ((rb ^ (rb >> 2)) & 3))) * 8;
  }

  f32x4 acc[4][4] = {};
  __builtin_amdgcn_global_load_lds(GBL(a0), LDSP(&sA[0][u0 * 8]), 16, 0, 0);
  __builtin_amdgcn_global_load_lds(GBL(a1), LDSP(&sA[0][u1 * 8]), 16, 0, 0);
  __builtin_amdgcn_global_load_lds(GBL(b0), LDSP(&sB[0][u0 * 8]), 16, 0, 0);
  __builtin_amdgcn_global_load_lds(GBL(b1), LDSP(&sB[0][u1 * 8]), 16, 0, 0);
  asm volatile("s_waitcnt vmcnt(0)" ::: "memory");
  __builtin_amdgcn_s_barrier();

  #pragma unroll 2
  for (int t = 0; t < 32; t++){
    const int cur = t & 1;
    if (t < 31){
      const int nb = cur ^ 1, ko = (t + 1) * 32;
      __builtin_amdgcn_global_load_lds(GBL(a0 + ko), LDSP(&sA[nb][u0 * 8]), 16, 0, 0);
      __builtin_amdgcn_global_load_lds(GBL(a1 + ko), LDSP(&sA[nb][u1 * 8]), 16, 0, 0);
      __builtin_amdgcn_global_load_lds(GBL(b0 + ko), LDSP(&sB[nb][u0 * 8]), 16, 0, 0);
      __builtin_amdgcn_global_load_lds(GBL(b1 + ko), LDSP(&sB[nb][u1 * 8]), 16, 0, 0);
    }
    bh8 af[4], bf[4];
    #pragma unroll
    for (int i = 0; i < 4; i++) af[i] = *(const bh8*)&sA[cur][aoff[i]];
    #pragma unroll
    for (int j = 0; j < 4; j++) bf[j] = *(const bh8*)&sB[cur][boff[j]];
    __builtin_amdgcn_s_setprio(1);
    #pragma unroll
    for (int i = 0; i < 4; i++)
      #pragma unroll
      for (int j = 0; j < 4; j++)
        acc[i][j] = __builtin_amdgcn_mfma_f32_16x16x32_bf16(af[i], bf[j], acc[i][j], 0, 0, 0);
    __builtin_amdgcn_s_setprio(0);
    asm volatile("s_waitcnt vmcnt(0)" ::: "memory");
    __builtin_amdgcn_s_barrier();
  }

  #pragma unroll
  for (int i = 0; i < 4; i++){
    int gm = blockIdx.x * 128 + wm + i * 16 + quad * 4;
    #pragma unroll
    for (int j = 0; j < 4; j++){
      int ng = blockIdx.y * 128 + wn + j * 16 + l16;
      float bv = bias[ng];
      #pragma unroll
      for (int r = 0; r < 4; r++)
        out[(size_t)(gm + r) * 1024 + ng] = acc[i][j][r] + bv;
    }
  }
}

extern "C" void kernel_launch(void* const* d_in, const int* in_sizes, int n_in,
                              void* d_out, int out_size, void* d_ws, size_t ws_size,
                              hipStream_t stream) {
  const float* x    = (const float*)d_in[0];   // [4,2048,1024]
  const float* Wqkv = (const float*)d_in[1];   // [1024,3072]
  const float* bqkv = (const float*)d_in[2];   // [3072]
  const float* Wo   = (const float*)d_in[3];   // [1024,1024]
  const float* bo   = (const float*)d_in[4];   // [1024]
  float* out = (float*)d_out;

  char* p = (char*)d_ws;
  ushort* xb  = (ushort*)p;                         // 16 MB (x bf16, later reused as O)
  ushort* WqT = (ushort*)(p + 16777216);            // 6 MB
  ushort* WoT = (ushort*)(p + 16777216 + 6291456);  // 2 MB
  ushort* Qd  = (ushort*)(p + 25165824);            // 16 MB each
  ushort* Kd  = (ushort*)(p + 25165824 + 16777216);
  ushort* Vt  = (ushort*)(p + 25165824 + 33554432);
  ushort* Od  = xb;                                 // x dead after gemm_qkv

  cast_x_kernel<<<8192, 256, 0, stream>>>((const float4*)x, xb);
  transpose_cast_kernel<<<dim3(96, 32), dim3(32, 8), 0, stream>>>(Wqkv, WqT, 1024, 3072);
  transpose_cast_kernel<<<dim3(32, 32), dim3(32, 8), 0, stream>>>(Wo, WoT, 1024, 1024);
  gemm_qkv_kernel<<<dim3(64, 24), 256, 0, stream>>>(xb, WqT, bqkv, Qd, Kd, Vt);
  flash_attn_kernel<<<dim3(64, 16), 256, 0, stream>>>(Qd, Kd, Vt, Od);
  gemm_out_kernel<<<dim3(64, 8), 256, 0, stream>>>(Od, WoT, bo, out);
}